// Round 18
// baseline (794.841 us; speedup 1.0000x reference)
//
#include <hip/hip_runtime.h>
#include <hip/hip_bf16.h>

#define NN 4096

typedef unsigned short u16;
using bf16x8 = __attribute__((ext_vector_type(8))) short;
using f32x4  = __attribute__((ext_vector_type(4))) float;

__device__ inline u16 f2bf(float f) {
    union { float f; unsigned u; } c; c.f = f;
    unsigned r = (c.u + 0x7fffu + ((c.u >> 16) & 1u)) >> 16;
    return (u16)r;
}
__device__ inline float bf2f(u16 b) {
    union { unsigned u; float f; } c; c.u = ((unsigned)b) << 16;
    return c.f;
}

__device__ inline void gld16(const void* g, void* l) {
    __builtin_amdgcn_global_load_lds(
        (const __attribute__((address_space(1))) void*)g,
        (__attribute__((address_space(3))) void*)l, 16, 0, 0);
}

// ---------------- f32 -> bf16 convert ----------------
__global__ __launch_bounds__(256) void cvt_bf16(const float* __restrict__ s,
                                                u16* __restrict__ d) {
    size_t i = ((size_t)blockIdx.x * 256 + threadIdx.x) * 8;
    float4 v0 = *(const float4*)(s + i);
    float4 v1 = *(const float4*)(s + i + 4);
    bf16x8 o;
    o[0] = (short)f2bf(v0.x); o[1] = (short)f2bf(v0.y);
    o[2] = (short)f2bf(v0.z); o[3] = (short)f2bf(v0.w);
    o[4] = (short)f2bf(v1.x); o[5] = (short)f2bf(v1.y);
    o[6] = (short)f2bf(v1.z); o[7] = (short)f2bf(v1.w);
    *(bf16x8*)(d + i) = o;
}

// ------- fused weight prep: WrT, WiT, S_A = WrT + WiT in one pass ----------
__global__ __launch_bounds__(256) void wprep(const float* __restrict__ Wr,
                                             const float* __restrict__ Wi,
                                             u16* __restrict__ WrT,
                                             u16* __restrict__ WiT,
                                             u16* __restrict__ SA) {
    __shared__ float tr[32][33], ti[32][33];
    int x  = blockIdx.x * 32 + threadIdx.x;
    int y0 = blockIdx.y * 32;
#pragma unroll
    for (int j = 0; j < 32; j += 8) {
        tr[threadIdx.y + j][threadIdx.x] = Wr[(size_t)(y0 + threadIdx.y + j) * NN + x];
        ti[threadIdx.y + j][threadIdx.x] = Wi[(size_t)(y0 + threadIdx.y + j) * NN + x];
    }
    __syncthreads();
    int x2 = blockIdx.y * 32 + threadIdx.x;
    int y2 = blockIdx.x * 32;
#pragma unroll
    for (int j = 0; j < 32; j += 8) {
        float a = tr[threadIdx.x][threadIdx.y + j];
        float b = ti[threadIdx.x][threadIdx.y + j];
        size_t o = (size_t)(y2 + threadIdx.y + j) * NN + x2;
        WrT[o] = f2bf(a);
        WiT[o] = f2bf(b);
        SA[o]  = f2bf(a + b);
    }
}

// ---------------- bf16 elementwise sum: d = a + b (S_B) ----------------
__global__ __launch_bounds__(256) void presum(const u16* __restrict__ a,
                                              const u16* __restrict__ b,
                                              u16* __restrict__ d) {
    size_t i = ((size_t)blockIdx.x * 256 + threadIdx.x) * 8;
    bf16x8 va = *(const bf16x8*)(a + i);
    bf16x8 vb = *(const bf16x8*)(b + i);
    bf16x8 o;
#pragma unroll
    for (int j = 0; j < 8; j++)
        o[j] = (short)f2bf(bf2f((u16)va[j]) + bf2f((u16)vb[j]));
    *(bf16x8*)(d + i) = o;
}

// ---------------- Karatsuba combine (streaming, R14-verified) ----------------
// outL holds M1, outR holds M3, M2 in ws.  Cr = M1-M2 ; Ci = M3-M1-M2.
__global__ __launch_bounds__(256) void combine(float* __restrict__ out,
                                               const float* __restrict__ M2) {
    size_t i = ((size_t)blockIdx.x * 256 + threadIdx.x) * 4;
    size_t m = i >> 12, n = i & 4095;
    float4 v1 = *(float4*)(out + m * 8192 + n);
    float4 v3 = *(float4*)(out + m * 8192 + 4096 + n);
    float4 v2 = *(const float4*)(M2 + m * 4096 + n);
    float4 cr, ci;
    cr.x = v1.x - v2.x; ci.x = v3.x - v1.x - v2.x;
    cr.y = v1.y - v2.y; ci.y = v3.y - v1.y - v2.y;
    cr.z = v1.z - v2.z; ci.z = v3.z - v1.z - v2.z;
    cr.w = v1.w - v2.w; ci.w = v3.w - v1.w - v2.w;
    *(float4*)(out + m * 8192 + n) = cr;
    *(float4*)(out + m * 8192 + 4096 + n) = ci;
}

// ---- sync primitives (rule #18: sched_barrier after inline waitcnt) ----
#define P_BAR  __builtin_amdgcn_s_barrier()
#define P_LGKM do { asm volatile("s_waitcnt lgkmcnt(0)" ::: "memory"); \
                    __builtin_amdgcn_sched_barrier(0); } while (0)
#define VMW(N) do { asm volatile("s_waitcnt vmcnt(" #N ")" ::: "memory"); \
                    __builtin_amdgcn_sched_barrier(0); } while (0)

// ====== 256x256, BK=64, 8-phase fine-interleaved NT GEMM (m201-faithful) =====
// C[i][j] = sum_k A[i][k]*B[j][k]. 512 thr = 8 waves (2M x 4N), wave tile
// 128x64. LDS: sA/sB [2buf][2half][128*64] bf16 = 128 KB. Per phase:
// {4 ds_read A-quadrant (ph0: +8 B-frags, register-resident for the K-tile);
//  1 half-tile stage (2 gld16); barrier; lgkmcnt(0); setprio+16 MFMA; barrier}.
// Counted vmcnt(4) ONLY at ph3/ph7 (never 0 in steady state).
// Staging rotation (dest globally dead at issue, proven by phase windows):
//   ph0-1: A(T1)->buf1.A (dead since prev ph7) ; ph2-3: B(T2)->buf0.B (dead
//   after ph0) ; ph4-5: A(T2)->buf0.A (dead after ph3) ; ph6-7: B(T3)->buf1.B
//   (dead after ph4). Gate at ph3: 12 outstanding -> VMW(4) leaves newest 4
//   (B(T2)); guarantees B(T1)+A(T1) for ph4. Gate at ph7: leaves B(T3);
//   guarantees A(T2)+B(T2) for next ph0.
// Addressing/swizzle identical to R5 (refcheck-passed, 0 bank conflicts):
// phys 16B-block pb at row r holds logical pb^(r&7); staged via
// inverse-permuted global source (gld_lds dest linear, rule #21).
#define MF(a_, b_, c_) __builtin_amdgcn_mfma_f32_16x16x32_bf16(a_, b_, c_, 0, 0, 0)

#define RDA(c, fr, k32) (*(const bf16x8*)&sA[c][wm][((fr)*16 + rl)*64 + ((((k32)*4 + kq) ^ rl7))*8])
#define RDB(c, fc, k32) (*(const bf16x8*)&sB[c][bh][(bro + (fc)*16 + rl)*64 + ((((k32)*4 + kq) ^ rl7))*8])

#define BLOADALL(c) do { \
    b00 = RDB(c,0,0); b01 = RDB(c,0,1); b10 = RDB(c,1,0); b11 = RDB(c,1,1); \
    b20 = RDB(c,2,0); b21 = RDB(c,2,1); b30 = RDB(c,3,0); b31 = RDB(c,3,1); } while (0)

#define STG_A(c, H, KT) do { \
    gld16(A + aoff + (size_t)((H)*128)*NN + (KT),    &sA[c][H][tid*8]); \
    gld16(A + aoff + (size_t)((H)*128+64)*NN + (KT), &sA[c][H][4096 + tid*8]); } while (0)
#define STG_B(c, H, KT) do { \
    gld16(Bp + boff + (size_t)((H)*128)*NN + (KT),    &sB[c][H][tid*8]); \
    gld16(Bp + boff + (size_t)((H)*128+64)*NN + (KT), &sB[c][H][4096 + tid*8]); } while (0)

#define PHASE(c, p, BLOAD, STG, GATE) do { \
    bf16x8 a0 = RDA(c, 2*(p), 0),   a1 = RDA(c, 2*(p), 1); \
    bf16x8 a2 = RDA(c, 2*(p)+1, 0), a3 = RDA(c, 2*(p)+1, 1); \
    BLOAD; \
    STG; \
    P_BAR; P_LGKM; \
    __builtin_amdgcn_s_setprio(1); \
    acc[2*(p)][0]   = MF(a0, b00, acc[2*(p)][0]); \
    acc[2*(p)][1]   = MF(a0, b10, acc[2*(p)][1]); \
    acc[2*(p)][2]   = MF(a0, b20, acc[2*(p)][2]); \
    acc[2*(p)][3]   = MF(a0, b30, acc[2*(p)][3]); \
    acc[2*(p)+1][0] = MF(a2, b00, acc[2*(p)+1][0]); \
    acc[2*(p)+1][1] = MF(a2, b10, acc[2*(p)+1][1]); \
    acc[2*(p)+1][2] = MF(a2, b20, acc[2*(p)+1][2]); \
    acc[2*(p)+1][3] = MF(a2, b30, acc[2*(p)+1][3]); \
    acc[2*(p)][0]   = MF(a1, b01, acc[2*(p)][0]); \
    acc[2*(p)][1]   = MF(a1, b11, acc[2*(p)][1]); \
    acc[2*(p)][2]   = MF(a1, b21, acc[2*(p)][2]); \
    acc[2*(p)][3]   = MF(a1, b31, acc[2*(p)][3]); \
    acc[2*(p)+1][0] = MF(a3, b01, acc[2*(p)+1][0]); \
    acc[2*(p)+1][1] = MF(a3, b11, acc[2*(p)+1][1]); \
    acc[2*(p)+1][2] = MF(a3, b21, acc[2*(p)+1][2]); \
    acc[2*(p)+1][3] = MF(a3, b31, acc[2*(p)+1][3]); \
    __builtin_amdgcn_s_setprio(0); \
    GATE; \
    P_BAR; \
} while (0)

// OM: 0 = bf16 out (stride NN), 1 = f32 out (stride cs)
template <int OM>
__global__ __launch_bounds__(512, 2) void gemm256p(
    const u16* __restrict__ A, const u16* __restrict__ Bp,
    u16* __restrict__ Cb, float* __restrict__ Cf, int cs) {
    __shared__ u16 sA[2][2][8192];
    __shared__ u16 sB[2][2][8192];

    const int brow = blockIdx.y * 256;
    const int bcol = blockIdx.x * 256;

    const int tid  = threadIdx.x;
    const int lane = tid & 63;
    const int wid  = tid >> 6;
    const int wm   = wid >> 2;          // 0..1  A half
    const int wn   = wid & 3;           // 0..3
    const int bh   = wn >> 1;           // B half
    const int bro  = (wn & 1) * 64;     // B row offset within half
    const int rl   = lane & 15;
    const int kq   = lane >> 4;
    const int rl7  = rl & 7;

    // staging map: thread t -> row sr = t>>3 (of each 64-row line), phys
    // 16B-block t&7; fetches global block (t&7)^(sr&7) (inverse swizzle)
    const int sr = tid >> 3;
    const int lb = (tid & 7) ^ (sr & 7);
    const size_t aoff = (size_t)(brow + sr) * NN + lb * 8;
    const size_t boff = (size_t)(bcol + sr) * NN + lb * 8;

    f32x4 acc[8][4] = {};
    bf16x8 b00, b01, b10, b11, b20, b21, b30, b31;

    // prologue: T0 -> buf0 (A,B), B(T1) -> buf1.B ; guarantee T0 (VMW(4)
    // keeps only B(T1) in flight)
    STG_A(0, 0, 0);  STG_A(0, 1, 0);
    STG_B(0, 0, 0);  STG_B(0, 1, 0);
    STG_B(1, 0, 64); STG_B(1, 1, 64);
    VMW(4); P_BAR;

    for (int i = 0; i < 31; ++i) {
        const size_t k1 = ((size_t)2 * i + 1) * 64;
        const size_t k2 = k1 + 64, k3 = k2 + 64;
        PHASE(0, 0, BLOADALL(0), STG_A(1, 0, k1), ((void)0));
        PHASE(0, 1, ((void)0),   STG_A(1, 1, k1), ((void)0));
        PHASE(0, 2, ((void)0),   STG_B(0, 0, k2), ((void)0));
        PHASE(0, 3, ((void)0),   STG_B(0, 1, k2), VMW(4));
        PHASE(1, 0, BLOADALL(1), STG_A(0, 0, k2), ((void)0));
        PHASE(1, 1, ((void)0),   STG_A(0, 1, k2), ((void)0));
        PHASE(1, 2, ((void)0),   STG_B(1, 0, k3), ((void)0));
        PHASE(1, 3, ((void)0),   STG_B(1, 1, k3), VMW(4));
    }
    // tail: T0=62, T1=63 (A(63) staged ph0/ph1; gates drain to 0)
    PHASE(0, 0, BLOADALL(0), STG_A(1, 0, 4032), ((void)0));
    PHASE(0, 1, ((void)0),   STG_A(1, 1, 4032), ((void)0));
    PHASE(0, 2, ((void)0),   ((void)0),         ((void)0));
    PHASE(0, 3, ((void)0),   ((void)0),         VMW(0));
    PHASE(1, 0, BLOADALL(1), ((void)0),         ((void)0));
    PHASE(1, 1, ((void)0),   ((void)0),         ((void)0));
    PHASE(1, 2, ((void)0),   ((void)0),         ((void)0));
    PHASE(1, 3, ((void)0),   ((void)0),         ((void)0));

    // epilogue (verified R5/R16): col = bcol + wn*64 + fc*16 + rl,
    // row = brow + wm*128 + fr*16 + kq*4 + e
    const int wr128 = wm * 128, wc64 = wn * 64;
    const int rg = kq * 4;
#pragma unroll
    for (int fr = 0; fr < 8; fr++)
#pragma unroll
        for (int fc = 0; fc < 4; fc++) {
            const int col = bcol + wc64 + fc * 16 + rl;
#pragma unroll
            for (int e = 0; e < 4; e++) {
                const int row = brow + wr128 + fr * 16 + rg + e;
                if (OM == 0)
                    Cb[(size_t)row * NN + col] = f2bf(acc[fr][fc][e]);
                else
                    Cf[(size_t)row * cs + col] = acc[fr][fc][e];
            }
        }
}

extern "C" void kernel_launch(void* const* d_in, const int* in_sizes, int n_in,
                              void* d_out, int out_size, void* d_ws, size_t ws_size,
                              hipStream_t stream) {
    const float* x  = (const float*)d_in[0];
    const float* Wr = (const float*)d_in[1];
    const float* Wi = (const float*)d_in[2];
    float* out = (float*)d_out;

    const size_t SZ = (size_t)NN * NN;
    u16* ws = (u16*)d_ws;
    u16* s0 = ws;            // xb   -> WrT
    u16* s1 = ws + SZ;       // Wrb  -> WiT
    u16* s2 = ws + 2 * SZ;   // Wib  -> S_A ; later (s2,s3) = M2 f32
    u16* s3 = ws + 3 * SZ;   // Rtr
    u16* s4 = ws + 4 * SZ;   // Rti
    u16* s5 = ws + 5 * SZ;   // S_B
    float* M2 = (float*)s2;  // 64 MB f32 over s2+s3 (both dead by M2 launch)

    // 1) convert inputs to bf16
    cvt_bf16<<<8192, 256, 0, stream>>>(x,  s0);
    cvt_bf16<<<8192, 256, 0, stream>>>(Wr, s1);
    cvt_bf16<<<8192, 256, 0, stream>>>(Wi, s2);

    // 2) pass 1 (bf16 out): Rtr = NT(Wr, x), Rti = NT(Wi, x)
    gemm256p<0><<<dim3(16, 16), 512, 0, stream>>>(s1, s0, s3, nullptr, 0);
    gemm256p<0><<<dim3(16, 16), 512, 0, stream>>>(s2, s0, s4, nullptr, 0);

    // 3) weight prep: WrT -> s0, WiT -> s1, S_A -> s2 ; S_B = Rtr+Rti -> s5
    wprep<<<dim3(128, 128), dim3(32, 8), 0, stream>>>(Wr, Wi, s0, s1, s2);
    presum<<<8192, 256, 0, stream>>>(s3, s4, s5);

    // 4) pass 2 via Karatsuba (order: M3, M1, then M2 into dead s2/s3)
    gemm256p<1><<<dim3(16, 16), 512, 0, stream>>>(s2, s5, nullptr, out + NN, 2 * NN); // M3
    gemm256p<1><<<dim3(16, 16), 512, 0, stream>>>(s0, s3, nullptr, out,      2 * NN); // M1
    gemm256p<1><<<dim3(16, 16), 512, 0, stream>>>(s1, s4, nullptr, M2,       NN);     // M2

    // 5) combine (streaming, full occupancy): Cr = M1-M2, Ci = M3-M1-M2
    combine<<<16384, 256, 0, stream>>>(out, M2);
}

// Round 19
// 738.796 us; speedup vs baseline: 1.0759x; 1.0759x over previous
//
#include <hip/hip_runtime.h>
#include <hip/hip_bf16.h>

#define NN 4096

typedef unsigned short u16;
using bf16x8 = __attribute__((ext_vector_type(8))) short;
using f32x4  = __attribute__((ext_vector_type(4))) float;

__device__ inline u16 f2bf(float f) {
    union { float f; unsigned u; } c; c.f = f;
    unsigned r = (c.u + 0x7fffu + ((c.u >> 16) & 1u)) >> 16;
    return (u16)r;
}
__device__ inline float bf2f(u16 b) {
    union { unsigned u; float f; } c; c.u = ((unsigned)b) << 16;
    return c.f;
}

__device__ inline void gld16(const void* g, void* l) {
    __builtin_amdgcn_global_load_lds(
        (const __attribute__((address_space(1))) void*)g,
        (__attribute__((address_space(3))) void*)l, 16, 0, 0);
}

// ---------------- f32 -> bf16 convert ----------------
__global__ __launch_bounds__(256) void cvt_bf16(const float* __restrict__ s,
                                                u16* __restrict__ d) {
    size_t i = ((size_t)blockIdx.x * 256 + threadIdx.x) * 8;
    float4 v0 = *(const float4*)(s + i);
    float4 v1 = *(const float4*)(s + i + 4);
    bf16x8 o;
    o[0] = (short)f2bf(v0.x); o[1] = (short)f2bf(v0.y);
    o[2] = (short)f2bf(v0.z); o[3] = (short)f2bf(v0.w);
    o[4] = (short)f2bf(v1.x); o[5] = (short)f2bf(v1.y);
    o[6] = (short)f2bf(v1.z); o[7] = (short)f2bf(v1.w);
    *(bf16x8*)(d + i) = o;
}

// ------- fused weight prep: WrT, WiT, S_A = WrT + WiT in one pass ----------
__global__ __launch_bounds__(256) void wprep(const float* __restrict__ Wr,
                                             const float* __restrict__ Wi,
                                             u16* __restrict__ WrT,
                                             u16* __restrict__ WiT,
                                             u16* __restrict__ SA) {
    __shared__ float tr[32][33], ti[32][33];
    int x  = blockIdx.x * 32 + threadIdx.x;
    int y0 = blockIdx.y * 32;
#pragma unroll
    for (int j = 0; j < 32; j += 8) {
        tr[threadIdx.y + j][threadIdx.x] = Wr[(size_t)(y0 + threadIdx.y + j) * NN + x];
        ti[threadIdx.y + j][threadIdx.x] = Wi[(size_t)(y0 + threadIdx.y + j) * NN + x];
    }
    __syncthreads();
    int x2 = blockIdx.y * 32 + threadIdx.x;
    int y2 = blockIdx.x * 32;
#pragma unroll
    for (int j = 0; j < 32; j += 8) {
        float a = tr[threadIdx.x][threadIdx.y + j];
        float b = ti[threadIdx.x][threadIdx.y + j];
        size_t o = (size_t)(y2 + threadIdx.y + j) * NN + x2;
        WrT[o] = f2bf(a);
        WiT[o] = f2bf(b);
        SA[o]  = f2bf(a + b);
    }
}

// ---------------- bf16 elementwise sum: d = a + b (S_B) ----------------
__global__ __launch_bounds__(256) void presum(const u16* __restrict__ a,
                                              const u16* __restrict__ b,
                                              u16* __restrict__ d) {
    size_t i = ((size_t)blockIdx.x * 256 + threadIdx.x) * 8;
    bf16x8 va = *(const bf16x8*)(a + i);
    bf16x8 vb = *(const bf16x8*)(b + i);
    bf16x8 o;
#pragma unroll
    for (int j = 0; j < 8; j++)
        o[j] = (short)f2bf(bf2f((u16)va[j]) + bf2f((u16)vb[j]));
    *(bf16x8*)(d + i) = o;
}

// ---------------- Karatsuba combine (streaming, R14-verified) ----------------
// outL holds M1, outR holds M3, M2 in ws.  Cr = M1-M2 ; Ci = M3-M1-M2.
__global__ __launch_bounds__(256) void combine(float* __restrict__ out,
                                               const float* __restrict__ M2) {
    size_t i = ((size_t)blockIdx.x * 256 + threadIdx.x) * 4;
    size_t m = i >> 12, n = i & 4095;
    float4 v1 = *(float4*)(out + m * 8192 + n);
    float4 v3 = *(float4*)(out + m * 8192 + 4096 + n);
    float4 v2 = *(const float4*)(M2 + m * 4096 + n);
    float4 cr, ci;
    cr.x = v1.x - v2.x; ci.x = v3.x - v1.x - v2.x;
    cr.y = v1.y - v2.y; ci.y = v3.y - v1.y - v2.y;
    cr.z = v1.z - v2.z; ci.z = v3.z - v1.z - v2.z;
    cr.w = v1.w - v2.w; ci.w = v3.w - v1.w - v2.w;
    *(float4*)(out + m * 8192 + n) = cr;
    *(float4*)(out + m * 8192 + 4096 + n) = ci;
}

// ---- sync primitives (rule #18: sched_barrier after inline waitcnt) ----
#define P_BAR  __builtin_amdgcn_s_barrier()
#define P_SCH  __builtin_amdgcn_sched_barrier(0)
#define P_LGKM do { asm volatile("s_waitcnt lgkmcnt(0)" ::: "memory"); \
                    __builtin_amdgcn_sched_barrier(0); } while (0)
#define LGKM4  do { asm volatile("s_waitcnt lgkmcnt(4)" ::: "memory"); \
                    __builtin_amdgcn_sched_barrier(0); } while (0)
#define VMW(N) do { asm volatile("s_waitcnt vmcnt(" #N ")" ::: "memory"); \
                    __builtin_amdgcn_sched_barrier(0); } while (0)

// ========== 256x256-tile, BK=32, 4-LDS-buffer deep-pipelined NT GEMM =========
// (R16-verified best: 127 us/GEMM, MfmaUtil ~46%, 0 bank conflicts.)
// C[i][j] = sum_k A[i][k]*B[j][k]. 512 thr = 8 waves (2M x 4N), wave tile
// 128x64. LDS = 4 buf x (A,B) x [256][32] bf16 = 128 KB (1 block/CU).
// Stage at step t targets buf (t+2)&3; vmcnt(4) at phase-top (never 0 until
// tail); all 12 ds_reads at step top with counted lgkmcnt(4) before CHAIN1
// (c-read drain hides under CHAIN1). LDS swizzle (R3-proven, 0 conflicts):
// phys 16B-block p at row r holds logical p^((r>>1)&3), via inverse-permuted
// global source (rule #21).
#define SGA(NB, KN) do { \
    gld16(A + aoff0 + (KN), &sm2[NB][0][tid * 8]); \
    gld16(A + aoff1 + (KN), &sm2[NB][0][4096 + tid * 8]); \
} while (0)
#define SGB(NB, KN) do { \
    gld16(Bp + boff0 + (KN), &sm2[NB][1][tid * 8]); \
    gld16(Bp + boff1 + (KN), &sm2[NB][1][4096 + tid * 8]); \
} while (0)

#define K256(CB, NB, KN, DOSTG, V) do { \
    bf16x8 a[4], b[4], c[4]; \
    VMW(V); P_BAR; P_SCH; \
    _Pragma("unroll") \
    for (int i_ = 0; i_ < 4; i_++) \
        a[i_] = *(const bf16x8*)&sm2[CB][0][(wr128 + i_ * 16 + rl) * 32 + kg]; \
    _Pragma("unroll") \
    for (int j_ = 0; j_ < 4; j_++) \
        b[j_] = *(const bf16x8*)&sm2[CB][1][(wc64 + j_ * 16 + rl) * 32 + kg]; \
    _Pragma("unroll") \
    for (int i_ = 0; i_ < 4; i_++) \
        c[i_] = *(const bf16x8*)&sm2[CB][0][(wr128 + 64 + i_ * 16 + rl) * 32 + kg]; \
    if (DOSTG) SGA(NB, KN); \
    LGKM4; \
    __builtin_amdgcn_s_setprio(1); \
    _Pragma("unroll") \
    for (int i_ = 0; i_ < 4; i_++) \
        _Pragma("unroll") \
        for (int j_ = 0; j_ < 4; j_++) \
            acc[i_][j_] = __builtin_amdgcn_mfma_f32_16x16x32_bf16(a[i_], b[j_], acc[i_][j_], 0, 0, 0); \
    __builtin_amdgcn_s_setprio(0); \
    if (DOSTG) SGB(NB, KN); \
    P_LGKM; \
    __builtin_amdgcn_s_setprio(1); \
    _Pragma("unroll") \
    for (int i_ = 0; i_ < 4; i_++) \
        _Pragma("unroll") \
        for (int j_ = 0; j_ < 4; j_++) \
            acc[4 + i_][j_] = __builtin_amdgcn_mfma_f32_16x16x32_bf16(c[i_], b[j_], acc[4 + i_][j_], 0, 0, 0); \
    __builtin_amdgcn_s_setprio(0); \
} while (0)

// OM: 0 = bf16 out (stride NN), 1 = f32 out (stride cs)
template <int OM>
__global__ __launch_bounds__(512, 2) void gemm256k(
    const u16* __restrict__ A, const u16* __restrict__ Bp,
    u16* __restrict__ Cb, float* __restrict__ Cf, int cs) {
    __shared__ u16 sm2[4][2][8192];

    const int brow = blockIdx.y * 256;
    const int bcol = blockIdx.x * 256;

    const int tid  = threadIdx.x;
    const int lane = tid & 63;
    const int wid  = tid >> 6;
    const int wr128 = (wid >> 2) * 128;
    const int wc64  = (wid & 3) * 64;
    const int rl = lane & 15;
    const int kq = lane >> 4;
    const int kg = (kq ^ ((rl >> 1) & 3)) * 8;

    const int r0 = tid >> 2;
    const int lb = (tid & 3) ^ ((r0 >> 1) & 3);
    const size_t aoff0 = (size_t)(brow + r0) * NN + lb * 8;
    const size_t aoff1 = aoff0 + (size_t)128 * NN;
    const size_t boff0 = (size_t)(bcol + r0) * NN + lb * 8;
    const size_t boff1 = boff0 + (size_t)128 * NN;

    f32x4 acc[8][4] = {};

    SGA(0, 0); SGB(0, 0); SGA(1, 32); SGB(1, 32);

    for (int tb = 0; tb < 31; ++tb) {
        const size_t k0 = (size_t)tb * 128;
        K256(0, 2, k0 + 64,  1, 4);
        K256(1, 3, k0 + 96,  1, 4);
        K256(2, 0, k0 + 128, 1, 4);
        K256(3, 1, k0 + 160, 1, 4);
    }
    K256(0, 2, 4032, 1, 4);
    K256(1, 3, 4064, 1, 4);
    K256(2, 0, 0,    0, 4);
    K256(3, 0, 0,    0, 0);

    const int rg = kq * 4;
#pragma unroll
    for (int fr = 0; fr < 8; fr++)
#pragma unroll
        for (int fc = 0; fc < 4; fc++) {
            const int col = bcol + wc64 + fc * 16 + rl;
#pragma unroll
            for (int e = 0; e < 4; e++) {
                const int row = brow + wr128 + fr * 16 + rg + e;
                if (OM == 0)
                    Cb[(size_t)row * NN + col] = f2bf(acc[fr][fc][e]);
                else
                    Cf[(size_t)row * cs + col] = acc[fr][fc][e];
            }
        }
}

extern "C" void kernel_launch(void* const* d_in, const int* in_sizes, int n_in,
                              void* d_out, int out_size, void* d_ws, size_t ws_size,
                              hipStream_t stream) {
    const float* x  = (const float*)d_in[0];
    const float* Wr = (const float*)d_in[1];
    const float* Wi = (const float*)d_in[2];
    float* out = (float*)d_out;

    const size_t SZ = (size_t)NN * NN;
    u16* ws = (u16*)d_ws;
    u16* s0 = ws;            // xb   -> WrT
    u16* s1 = ws + SZ;       // Wrb  -> WiT
    u16* s2 = ws + 2 * SZ;   // Wib  -> S_A ; later (s2,s3) = M2 f32
    u16* s3 = ws + 3 * SZ;   // Rtr
    u16* s4 = ws + 4 * SZ;   // Rti
    u16* s5 = ws + 5 * SZ;   // S_B
    float* M2 = (float*)s2;  // 64 MB f32 over s2+s3 (both dead by M2 launch)

    // 1) convert inputs to bf16
    cvt_bf16<<<8192, 256, 0, stream>>>(x,  s0);
    cvt_bf16<<<8192, 256, 0, stream>>>(Wr, s1);
    cvt_bf16<<<8192, 256, 0, stream>>>(Wi, s2);

    // 2) pass 1 on gemm256k (bf16 out): Rtr = NT(Wr, x), Rti = NT(Wi, x)
    gemm256k<0><<<dim3(16, 16), 512, 0, stream>>>(s1, s0, s3, nullptr, 0);
    gemm256k<0><<<dim3(16, 16), 512, 0, stream>>>(s2, s0, s4, nullptr, 0);

    // 3) weight prep: WrT -> s0, WiT -> s1, S_A -> s2 ; S_B = Rtr+Rti -> s5
    wprep<<<dim3(128, 128), dim3(32, 8), 0, stream>>>(Wr, Wi, s0, s1, s2);
    presum<<<8192, 256, 0, stream>>>(s3, s4, s5);

    // 4) pass 2 via Karatsuba (order: M3, M1, then M2 into dead s2/s3)
    gemm256k<1><<<dim3(16, 16), 512, 0, stream>>>(s2, s5, nullptr, out + NN, 2 * NN); // M3
    gemm256k<1><<<dim3(16, 16), 512, 0, stream>>>(s0, s3, nullptr, out,      2 * NN); // M1
    gemm256k<1><<<dim3(16, 16), 512, 0, stream>>>(s1, s4, nullptr, M2,       NN);     // M2

    // 5) combine (streaming, full occupancy): Cr = M1-M2, Ci = M3-M1-M2
    combine<<<16384, 256, 0, stream>>>(out, M2);
}